// Round 5
// baseline (87.841 us; speedup 1.0000x reference)
//
#include <hip/hip_runtime.h>
#include <math.h>

#define B 4
#define TQ 512
#define TV 1024
#define DQ 256
#define DV 256
#define UNITS 64
#define NQROW (B * TQ)   // 2048
#define NKROW (B * TV)   // 4096

#define CEXP  2.885390081777927f    // 2*log2(e): exp(2x) == exp2(CEXP*x)
#define LOG2E 1.4426950408889634f

__device__ __forceinline__ float fast_exp2(float x) {
#if __has_builtin(__builtin_amdgcn_exp2f)
    return __builtin_amdgcn_exp2f(x);
#else
    return __expf(0.6931471805599453f * x);
#endif
}

__device__ __forceinline__ float wave_max(float v) {
    #pragma unroll
    for (int off = 32; off > 0; off >>= 1)
        v = fmaxf(v, __shfl_xor(v, off, 64));
    return v;
}
__device__ __forceinline__ float wave_sum(float v) {
    #pragma unroll
    for (int off = 32; off > 0; off >>= 1)
        v += __shfl_xor(v, off, 64);
    return v;
}

// ---- projections: 8 rows per wave (weights amortized), 32 rows per block ----
// Blocks 0..63 are query rows -> Eq row-major [NQROW][UNITS].
// Blocks 64..191 are value rows -> EkT transposed [UNITS][NKROW] via LDS bounce.
#define PRB 32
__global__ __launch_bounds__(256) void proj_kernel(
        const float* __restrict__ query, const float* __restrict__ value,
        const float* __restrict__ w1, const float* __restrict__ w2,
        float* __restrict__ Eq, float* __restrict__ EkT) {
    __shared__ float lt[64][36];           // padded: 36*4B -> 16B-aligned segs
    const int tid = threadIdx.x;
    const int u   = tid & 63;
    const int wid = __builtin_amdgcn_readfirstlane(tid >> 6);
    const int row0 = blockIdx.x * PRB + wid * 8;
    const bool isq = row0 < NQROW;
    const float* w  = isq ? w1 : w2;
    const float* in = isq ? query + (size_t)row0 * DQ
                          : value + (size_t)(row0 - NQROW) * DV;
    float a[8] = {};
    #pragma unroll 8
    for (int c = 0; c < DQ / 4; ++c) {
        const float wv0 = w[(4 * c + 0) * UNITS + u];
        const float wv1 = w[(4 * c + 1) * UNITS + u];
        const float wv2 = w[(4 * c + 2) * UNITS + u];
        const float wv3 = w[(4 * c + 3) * UNITS + u];
        #pragma unroll
        for (int r = 0; r < 8; ++r) {
            float4 t = *(const float4*)(in + (size_t)r * DQ + 4 * c);
            a[r] = fmaf(t.x, wv0, a[r]);
            a[r] = fmaf(t.y, wv1, a[r]);
            a[r] = fmaf(t.z, wv2, a[r]);
            a[r] = fmaf(t.w, wv3, a[r]);
        }
    }
    if (isq) {
        #pragma unroll
        for (int r = 0; r < 8; ++r)
            Eq[(size_t)(row0 + r) * UNITS + u] = fast_exp2(CEXP * a[r]);
    } else {
        #pragma unroll
        for (int r = 0; r < 8; ++r)
            lt[u][wid * 8 + r] = fast_exp2(CEXP * a[r]);
        __syncthreads();
        const int uu = tid >> 2, seg = tid & 3;
        const int col = (blockIdx.x * PRB - NQROW) + seg * 8;
        float4 v0 = *(const float4*)&lt[uu][seg * 8];
        float4 v1 = *(const float4*)&lt[uu][seg * 8 + 4];
        float* dst = EkT + (size_t)uu * NKROW + col;
        *(float4*)(dst)     = v0;
        *(float4*)(dst + 4) = v1;
    }
}

// ---- scores + softmax: coalesced EkT loads (lane = v), QB q-rows per block --
#define QB 4
#define SNT 512
#define SNW (SNT / 64)
// grid = NQROW/QB = 512 blocks, 512 threads; thread owns v = {2*tid, 2*tid+1}
__global__ __launch_bounds__(SNT) void score_kernel(
        const float* __restrict__ Eq,      // [NQROW][UNITS]
        const float* __restrict__ EkT,     // [UNITS][NKROW]
        const float* __restrict__ scale,   // [UNITS]
        float* __restrict__ out_attn) {    // [NQROW][TV]
    __shared__ float q_lds[QB][UNITS];
    __shared__ float s_lds[UNITS];
    __shared__ float redm[QB][SNW];
    __shared__ float reds[QB][SNW];

    const int tid = threadIdx.x, lane = tid & 63, wid = tid >> 6;
    int bid = blockIdx.x;
    bid = (bid & 7) * ((NQROW / QB) >> 3) + (bid >> 3);   // XCD swizzle, bijective
    const int b  = bid / (TQ / QB);
    const int q0 = (bid % (TQ / QB)) * QB;

    if (tid < QB * UNITS)
        q_lds[tid >> 6][tid & 63] =
            Eq[(size_t)(b * TQ + q0 + (tid >> 6)) * UNITS + (tid & 63)];
    else if (tid < QB * UNITS + UNITS)
        s_lds[tid - QB * UNITS] = scale[tid - QB * UNITS];
    __syncthreads();

    const float* ekc = EkT + (size_t)b * TV + 2 * tid;
    float2 acc[QB];
    #pragma unroll
    for (int q = 0; q < QB; ++q) { acc[q].x = 0.f; acc[q].y = 0.f; }

    #pragma unroll 4
    for (int u = 0; u < UNITS; ++u) {
        float2 ek = *(const float2*)(ekc + (size_t)u * NKROW);
        const float s = s_lds[u];
        #pragma unroll
        for (int q = 0; q < QB; ++q) {
            const float eq = q_lds[q][u];
            float t0 = fmaf(eq, ek.x, 1.f);
            float t1 = fmaf(eq, ek.y, 1.f);
            acc[q].x = fmaf(s, __builtin_amdgcn_rcpf(t0), acc[q].x);
            acc[q].y = fmaf(s, __builtin_amdgcn_rcpf(t1), acc[q].y);
        }
    }

    // scores (shift-invariant): x = -2 * acc
    float x0[QB], x1[QB], m[QB];
    #pragma unroll
    for (int q = 0; q < QB; ++q) {
        x0[q] = -2.f * acc[q].x;
        x1[q] = -2.f * acc[q].y;
        m[q] = wave_max(fmaxf(x0[q], x1[q]));
        if (lane == 0) redm[q][wid] = m[q];
    }
    __syncthreads();
    #pragma unroll
    for (int q = 0; q < QB; ++q) {
        float mm = redm[q][0];
        #pragma unroll
        for (int i = 1; i < SNW; ++i) mm = fmaxf(mm, redm[q][i]);
        m[q] = mm;
    }
    float e0[QB], e1[QB];
    #pragma unroll
    for (int q = 0; q < QB; ++q) {
        const float mm = m[q] * LOG2E;
        e0[q] = fast_exp2(fmaf(x0[q], LOG2E, -mm));
        e1[q] = fast_exp2(fmaf(x1[q], LOG2E, -mm));
        float s = wave_sum(e0[q] + e1[q]);
        if (lane == 0) reds[q][wid] = s;
    }
    __syncthreads();
    #pragma unroll
    for (int q = 0; q < QB; ++q) {
        float ss = reds[q][0];
        #pragma unroll
        for (int i = 1; i < SNW; ++i) ss += reds[q][i];
        const float inv = __builtin_amdgcn_rcpf(ss);
        float2 o; o.x = e0[q] * inv; o.y = e1[q] * inv;
        float* arow = out_attn + (size_t)(b * TQ + q0 + q) * TV;
        *(float2*)(arow + 2 * tid) = o;
    }
}

// ---- context partial: QC q-rows x TV/SPLIT v-range per block ----
template <int QC, int SPLIT>
__global__ __launch_bounds__(512) void ctx_kernel(
        const float* __restrict__ attn,    // [NQROW][TV]
        const float* __restrict__ value,   // [B][TV][DV]
        float* __restrict__ dst) {         // [SPLIT][NQROW][DV]
    constexpr int TVC = TV / SPLIT;
    constexpr int QT  = QC / 2;            // q rows per thread (512 thr / 256 d)
    const int tid = threadIdx.x;
    constexpr int G = (NQROW / QC) * SPLIT;
    int bid = blockIdx.x;
    bid = (bid & 7) * (G >> 3) + (bid >> 3);   // XCD swizzle (G % 8 == 0)
    const int qc = bid / SPLIT, vs = bid % SPLIT;
    const int b  = qc / (TQ / QC);
    const int q0 = (qc % (TQ / QC)) * QC;
    const int v0 = vs * TVC;
    const int d  = tid & (DV - 1);
    const int qh = __builtin_amdgcn_readfirstlane(tid >> 8) * QT;

    const float* ab = attn + (size_t)(b * TQ + q0 + qh) * TV + v0;
    const float* vb = value + ((size_t)b * TV + v0) * DV + d;

    float acc[QT] = {};
    #pragma unroll 2
    for (int v4 = 0; v4 < TVC / 4; ++v4) {
        float4 aq[QT];
        #pragma unroll
        for (int j = 0; j < QT; ++j)
            aq[j] = *(const float4*)(ab + (size_t)j * TV + v4 * 4);
        #pragma unroll
        for (int k = 0; k < 4; ++k) {
            float val = vb[(size_t)(v4 * 4 + k) * DV];
            #pragma unroll
            for (int j = 0; j < QT; ++j)
                acc[j] = fmaf(((const float*)&aq[j])[k], val, acc[j]);
        }
    }
    float* o = dst + (size_t)vs * (NQROW * DV) + (size_t)(b * TQ + q0 + qh) * DV + d;
    #pragma unroll
    for (int j = 0; j < QT; ++j)
        o[(size_t)j * DV] = acc[j];
}

// out[i] = sum over 4 partials
__global__ __launch_bounds__(256) void reduce_kernel(
        const float* __restrict__ part, float* __restrict__ out) {
    constexpr size_t S = (size_t)NQROW * DV / 4;   // float4 count per partial
    const size_t i = (size_t)blockIdx.x * 256 + threadIdx.x;
    const float4* p = (const float4*)part;
    float4 a = p[i], b4 = p[i + S], c = p[i + 2 * S], d4 = p[i + 3 * S];
    float4 r;
    r.x = (a.x + b4.x) + (c.x + d4.x);
    r.y = (a.y + b4.y) + (c.y + d4.y);
    r.z = (a.z + b4.z) + (c.z + d4.z);
    r.w = (a.w + b4.w) + (c.w + d4.w);
    ((float4*)out)[i] = r;
}

extern "C" void kernel_launch(void* const* d_in, const int* in_sizes, int n_in,
                              void* d_out, int out_size, void* d_ws, size_t ws_size,
                              hipStream_t stream) {
    const float* query = (const float*)d_in[0];
    const float* value = (const float*)d_in[1];
    const float* w1    = (const float*)d_in[2];
    const float* w2    = (const float*)d_in[3];
    const float* scale = (const float*)d_in[4];

    float* out      = (float*)d_out;
    float* out_ctx  = out;                         // [NQROW*DV]
    float* out_attn = out + (size_t)NQROW * DV;    // [NQROW*TV]

    float* Eq   = (float*)d_ws;                    // NQROW*UNITS floats
    float* EkT  = Eq + (size_t)NQROW * UNITS;      // UNITS*NKROW floats
    float* part = EkT + (size_t)UNITS * NKROW;     // 4 * NQROW*DV floats

    const size_t need = ((size_t)NQROW * UNITS + (size_t)UNITS * NKROW +
                         (size_t)4 * NQROW * DV) * sizeof(float);

    proj_kernel<<<dim3((NQROW + NKROW) / PRB), 256, 0, stream>>>(
        query, value, w1, w2, Eq, EkT);
    score_kernel<<<dim3(NQROW / QB), SNT, 0, stream>>>(Eq, EkT, scale, out_attn);
    if (ws_size >= need) {
        ctx_kernel<16, 4><<<dim3((NQROW / 16) * 4), 512, 0, stream>>>(out_attn, value, part);
        reduce_kernel<<<dim3(NQROW * DV / 4 / 256), 256, 0, stream>>>(part, out_ctx);
    } else {
        ctx_kernel<8, 1><<<dim3(NQROW / 8), 512, 0, stream>>>(out_attn, value, out_ctx);
    }
}

// Round 6
// 60.063 us; speedup vs baseline: 1.4625x; 1.4625x over previous
//
#include <hip/hip_runtime.h>
#include <math.h>

#define B 4
#define TQ 512
#define TV 1024
#define DQ 256
#define DV 256
#define UNITS 64
#define NQROW (B * TQ)   // 2048
#define NKROW (B * TV)   // 4096

#define CEXP  2.885390081777927f    // 2*log2(e): exp(2x) == exp2(CEXP*x)
#define LOG2E 1.4426950408889634f

__device__ __forceinline__ float fast_exp2(float x) {
#if __has_builtin(__builtin_amdgcn_exp2f)
    return __builtin_amdgcn_exp2f(x);
#else
    return __expf(0.6931471805599453f * x);
#endif
}

__device__ __forceinline__ float wave_max(float v) {
    #pragma unroll
    for (int off = 32; off > 0; off >>= 1)
        v = fmaxf(v, __shfl_xor(v, off, 64));
    return v;
}
__device__ __forceinline__ float wave_sum(float v) {
    #pragma unroll
    for (int off = 32; off > 0; off >>= 1)
        v += __shfl_xor(v, off, 64);
    return v;
}

// ---- projections: 2 rows/wave, 8 rows/block, rows staged via LDS ----
// Blocks 0..255: query rows -> Eq row-major [NQROW][UNITS].
// Blocks 256..767: value rows -> EkT transposed [UNITS][NKROW] via LDS bounce.
#define RPB 8
__global__ __launch_bounds__(256) void proj_kernel(
        const float* __restrict__ query, const float* __restrict__ value,
        const float* __restrict__ w1, const float* __restrict__ w2,
        float* __restrict__ Eq, float* __restrict__ EkT) {
    __shared__ float rows[RPB][DQ];        // 8 KB, staged coalesced
    __shared__ float lt[64][RPB + 4];      // k transpose bounce (padded)
    const int tid = threadIdx.x;
    const int u   = tid & 63;
    const int wid = tid >> 6;
    const int row0 = blockIdx.x * RPB;     // block's first row (global index)
    const bool isq = row0 < NQROW;
    const float* in = isq ? query + (size_t)row0 * DQ
                          : value + (size_t)(row0 - NQROW) * DQ;
    const float* w  = isq ? w1 : w2;

    // stage 8 rows (2048 floats) with coalesced float4 loads
    {
        const float4* src = (const float4*)in;
        float4* dst = (float4*)&rows[0][0];
        dst[tid]       = src[tid];
        dst[tid + 256] = src[tid + 256];
    }
    __syncthreads();

    // each wave computes 2 rows (r0, r0+1) for all 64 u (lane = u)
    const int r0 = wid * 2;
    float a0 = 0.f, a1 = 0.f, b0 = 0.f, b1 = 0.f;
    #pragma unroll 8
    for (int c = 0; c < DQ / 4; ++c) {
        const float w0 = w[(4 * c + 0) * UNITS + u];
        const float w1v = w[(4 * c + 1) * UNITS + u];
        const float w2v = w[(4 * c + 2) * UNITS + u];
        const float w3v = w[(4 * c + 3) * UNITS + u];
        const float4 t0 = *(const float4*)&rows[r0][4 * c];
        const float4 t1 = *(const float4*)&rows[r0 + 1][4 * c];
        a0 = fmaf(t0.x, w0, a0);  a1 = fmaf(t0.y, w1v, a1);
        a0 = fmaf(t0.z, w2v, a0); a1 = fmaf(t0.w, w3v, a1);
        b0 = fmaf(t1.x, w0, b0);  b1 = fmaf(t1.y, w1v, b1);
        b0 = fmaf(t1.z, w2v, b0); b1 = fmaf(t1.w, w3v, b1);
    }
    const float ea = fast_exp2(CEXP * (a0 + a1));
    const float eb = fast_exp2(CEXP * (b0 + b1));

    if (isq) {
        Eq[(size_t)(row0 + r0) * UNITS + u]     = ea;
        Eq[(size_t)(row0 + r0 + 1) * UNITS + u] = eb;
    } else {
        lt[u][r0]     = ea;
        lt[u][r0 + 1] = eb;
    }
    __syncthreads();
    if (!isq) {
        // write EkT[u][col0 .. col0+7]: 512 floats, 256 threads -> float2 each
        const int uu = tid >> 2, p = tid & 3;
        const int col0 = row0 - NQROW;
        float2 v2;
        v2.x = lt[uu][2 * p];
        v2.y = lt[uu][2 * p + 1];
        *(float2*)(EkT + (size_t)uu * NKROW + col0 + 2 * p) = v2;
    }
}

// ---- scores + softmax: coalesced EkT loads (lane = v), QB q-rows per block --
#define QB 4
#define SNT 512
#define SNW (SNT / 64)
// grid = NQROW/QB = 512 blocks, 512 threads; thread owns v = {2*tid, 2*tid+1}
__global__ __launch_bounds__(SNT) void score_kernel(
        const float* __restrict__ Eq,      // [NQROW][UNITS]
        const float* __restrict__ EkT,     // [UNITS][NKROW]
        const float* __restrict__ scale,   // [UNITS]
        float* __restrict__ out_attn) {    // [NQROW][TV]
    __shared__ float q_lds[QB][UNITS];
    __shared__ float s_lds[UNITS];
    __shared__ float redm[QB][SNW];
    __shared__ float reds[QB][SNW];

    const int tid = threadIdx.x, lane = tid & 63, wid = tid >> 6;
    int bid = blockIdx.x;
    bid = (bid & 7) * ((NQROW / QB) >> 3) + (bid >> 3);   // XCD swizzle, bijective
    const int b  = bid / (TQ / QB);
    const int q0 = (bid % (TQ / QB)) * QB;

    if (tid < QB * UNITS)
        q_lds[tid >> 6][tid & 63] =
            Eq[(size_t)(b * TQ + q0 + (tid >> 6)) * UNITS + (tid & 63)];
    else if (tid < QB * UNITS + UNITS)
        s_lds[tid - QB * UNITS] = scale[tid - QB * UNITS];
    __syncthreads();

    const float* ekc = EkT + (size_t)b * TV + 2 * tid;
    float2 acc[QB];
    #pragma unroll
    for (int q = 0; q < QB; ++q) { acc[q].x = 0.f; acc[q].y = 0.f; }

    #pragma unroll 8
    for (int u = 0; u < UNITS; ++u) {
        float2 ek = *(const float2*)(ekc + (size_t)u * NKROW);
        const float s = s_lds[u];
        #pragma unroll
        for (int q = 0; q < QB; ++q) {
            const float eq = q_lds[q][u];
            float t0 = fmaf(eq, ek.x, 1.f);
            float t1 = fmaf(eq, ek.y, 1.f);
            acc[q].x = fmaf(s, __builtin_amdgcn_rcpf(t0), acc[q].x);
            acc[q].y = fmaf(s, __builtin_amdgcn_rcpf(t1), acc[q].y);
        }
    }

    // scores (shift-invariant): x = -2 * acc
    float x0[QB], x1[QB], m[QB];
    #pragma unroll
    for (int q = 0; q < QB; ++q) {
        x0[q] = -2.f * acc[q].x;
        x1[q] = -2.f * acc[q].y;
        m[q] = wave_max(fmaxf(x0[q], x1[q]));
        if (lane == 0) redm[q][wid] = m[q];
    }
    __syncthreads();
    #pragma unroll
    for (int q = 0; q < QB; ++q) {
        float mm = redm[q][0];
        #pragma unroll
        for (int i = 1; i < SNW; ++i) mm = fmaxf(mm, redm[q][i]);
        m[q] = mm;
    }
    float e0[QB], e1[QB];
    #pragma unroll
    for (int q = 0; q < QB; ++q) {
        const float mm = m[q] * LOG2E;
        e0[q] = fast_exp2(fmaf(x0[q], LOG2E, -mm));
        e1[q] = fast_exp2(fmaf(x1[q], LOG2E, -mm));
        float s = wave_sum(e0[q] + e1[q]);
        if (lane == 0) reds[q][wid] = s;
    }
    __syncthreads();
    #pragma unroll
    for (int q = 0; q < QB; ++q) {
        float ss = reds[q][0];
        #pragma unroll
        for (int i = 1; i < SNW; ++i) ss += reds[q][i];
        const float inv = __builtin_amdgcn_rcpf(ss);
        float2 o; o.x = e0[q] * inv; o.y = e1[q] * inv;
        float* arow = out_attn + (size_t)(b * TQ + q0 + q) * TV;
        *(float2*)(arow + 2 * tid) = o;
    }
}

// ---- context partial: QC q-rows x TV/SPLIT v-range per block ----
template <int QC, int SPLIT>
__global__ __launch_bounds__(512) void ctx_kernel(
        const float* __restrict__ attn,    // [NQROW][TV]
        const float* __restrict__ value,   // [B][TV][DV]
        float* __restrict__ dst) {         // [SPLIT][NQROW][DV]
    constexpr int TVC = TV / SPLIT;
    constexpr int QT  = QC / 2;            // q rows per thread (512 thr / 256 d)
    const int tid = threadIdx.x;
    constexpr int G = (NQROW / QC) * SPLIT;
    int bid = blockIdx.x;
    bid = (bid & 7) * (G >> 3) + (bid >> 3);   // XCD swizzle (G % 8 == 0)
    const int qc = bid / SPLIT, vs = bid % SPLIT;
    const int b  = qc / (TQ / QC);
    const int q0 = (qc % (TQ / QC)) * QC;
    const int v0 = vs * TVC;
    const int d  = tid & (DV - 1);
    const int qh = __builtin_amdgcn_readfirstlane(tid >> 8) * QT;

    const float* ab = attn + (size_t)(b * TQ + q0 + qh) * TV + v0;
    const float* vb = value + ((size_t)b * TV + v0) * DV + d;

    float acc[QT] = {};
    #pragma unroll 2
    for (int v4 = 0; v4 < TVC / 4; ++v4) {
        float4 aq[QT];
        #pragma unroll
        for (int j = 0; j < QT; ++j)
            aq[j] = *(const float4*)(ab + (size_t)j * TV + v4 * 4);
        #pragma unroll
        for (int k = 0; k < 4; ++k) {
            float val = vb[(size_t)(v4 * 4 + k) * DV];
            #pragma unroll
            for (int j = 0; j < QT; ++j)
                acc[j] = fmaf(((const float*)&aq[j])[k], val, acc[j]);
        }
    }
    float* o = dst + (size_t)vs * (NQROW * DV) + (size_t)(b * TQ + q0 + qh) * DV + d;
    #pragma unroll
    for (int j = 0; j < QT; ++j)
        o[(size_t)j * DV] = acc[j];
}

// out[i] = sum over 4 partials
__global__ __launch_bounds__(256) void reduce_kernel(
        const float* __restrict__ part, float* __restrict__ out) {
    constexpr size_t S = (size_t)NQROW * DV / 4;   // float4 count per partial
    const size_t i = (size_t)blockIdx.x * 256 + threadIdx.x;
    const float4* p = (const float4*)part;
    float4 a = p[i], b4 = p[i + S], c = p[i + 2 * S], d4 = p[i + 3 * S];
    float4 r;
    r.x = (a.x + b4.x) + (c.x + d4.x);
    r.y = (a.y + b4.y) + (c.y + d4.y);
    r.z = (a.z + b4.z) + (c.z + d4.z);
    r.w = (a.w + b4.w) + (c.w + d4.w);
    ((float4*)out)[i] = r;
}

extern "C" void kernel_launch(void* const* d_in, const int* in_sizes, int n_in,
                              void* d_out, int out_size, void* d_ws, size_t ws_size,
                              hipStream_t stream) {
    const float* query = (const float*)d_in[0];
    const float* value = (const float*)d_in[1];
    const float* w1    = (const float*)d_in[2];
    const float* w2    = (const float*)d_in[3];
    const float* scale = (const float*)d_in[4];

    float* out      = (float*)d_out;
    float* out_ctx  = out;                         // [NQROW*DV]
    float* out_attn = out + (size_t)NQROW * DV;    // [NQROW*TV]

    float* Eq   = (float*)d_ws;                    // NQROW*UNITS floats
    float* EkT  = Eq + (size_t)NQROW * UNITS;      // UNITS*NKROW floats
    float* part = EkT + (size_t)UNITS * NKROW;     // 4 * NQROW*DV floats

    const size_t need = ((size_t)NQROW * UNITS + (size_t)UNITS * NKROW +
                         (size_t)4 * NQROW * DV) * sizeof(float);

    proj_kernel<<<dim3((NQROW + NKROW) / RPB), 256, 0, stream>>>(
        query, value, w1, w2, Eq, EkT);
    score_kernel<<<dim3(NQROW / QB), SNT, 0, stream>>>(Eq, EkT, scale, out_attn);
    if (ws_size >= need) {
        ctx_kernel<16, 4><<<dim3((NQROW / 16) * 4), 512, 0, stream>>>(out_attn, value, part);
        reduce_kernel<<<dim3(NQROW * DV / 4 / 256), 256, 0, stream>>>(part, out_ctx);
    } else {
        ctx_kernel<8, 1><<<dim3(NQROW / 8), 512, 0, stream>>>(out_attn, value, out_ctx);
    }
}